// Round 7
// baseline (260.579 us; speedup 1.0000x reference)
//
#include <hip/hip_runtime.h>

#define EMBED 128
#define NPATH 32
#define BATCH 4096
#define DIN 768
#define C1 128
#define C2 32

__device__ __forceinline__ float4 chain_step(float4 x, float4 y, float4 wm, float4 bm) {
    float4 r;
    r.x = fmaxf(fmaf(x.x * wm.x, y.x, bm.x), 0.f);
    r.y = fmaxf(fmaf(x.y * wm.y, y.y, bm.y), 0.f);
    r.z = fmaxf(fmaf(x.z * wm.z, y.z, bm.z), 0.f);
    r.w = fmaxf(fmaf(x.w * wm.w, y.w, bm.w), 0.f);
    return r;
}

// One group-unit for batch row b. 256 threads: dl = tid&31 owns dims 4*dl..4*dl+3
// (float4), pq = tid>>5 (0..7) owns paths p = pq, pq+8, pq+16, pq+24.
// FINAL (rounds 0-6): memory-pattern-bound at ~3.55 TB/s / ~83us — five
// structural variants plateau here; random 512B gathers over the 51MB
// E-table are the floor. W/B selection via LDS gather (VALU-lean, Occ 62%).
template<int L>
__device__ __forceinline__ void group_body(
    int b, const int* __restrict__ ent, const int* __restrict__ mid,
    const float* __restrict__ counts, const float4* __restrict__ E4,
    const float4* __restrict__ W4, const float4* __restrict__ B4,
    float* __restrict__ h, int gcol, int* s_idx, float4* s_red, float4* s_wb)
{
    const int tid = threadIdx.x;
    const int dl = tid & 31;
    const int pq = tid >> 5;

    int* s_ent = s_idx;
    int* s_mid = s_idx + NPATH * (L + 1);
    float* s_cnt = (float*)(s_idx + NPATH * (2 * L + 1));
    float4* s_w4 = s_wb;          // [3][32] float4
    float4* s_b4 = s_wb + 96;     // [3][32] float4

    const int* entb = ent + (size_t)b * (NPATH * (L + 1));
    const int* midb = mid + (size_t)b * (NPATH * L);
    for (int i = tid; i < NPATH * (L + 1); i += 256) s_ent[i] = entb[i];
    for (int i = tid; i < NPATH * L; i += 256) s_mid[i] = midb[i];
    if (tid < NPATH) s_cnt[tid] = counts[(size_t)b * NPATH + tid];
    if (tid < 96) { s_w4[tid] = W4[tid]; s_b4[tid] = B4[tid]; }
    __syncthreads();

    float4 n1 = make_float4(0.f, 0.f, 0.f, 0.f);
    float4 n2 = make_float4(0.f, 0.f, 0.f, 0.f);

#pragma unroll 2
    for (int j = 0; j < NPATH / 8; ++j) {
        const int p = pq + 8 * j;
        int ei[L + 1], mi[L];
#pragma unroll
        for (int i = 0; i <= L; ++i) ei[i] = s_ent[p * (L + 1) + i];
#pragma unroll
        for (int i = 0; i < L; ++i) mi[i] = s_mid[p * L + i];

        float4 e[L + 1];
#pragma unroll
        for (int i = 0; i <= L; ++i) e[i] = E4[(size_t)ei[i] * 32 + dl];

        float4 wv[L], bv[L];
#pragma unroll
        for (int i = 0; i < L; ++i) {
            wv[i] = s_w4[mi[i] * 32 + dl];
            bv[i] = s_b4[mi[i] * 32 + dl];
        }
        const float c = s_cnt[p];

        float4 x = e[0];
#pragma unroll
        for (int i = 0; i < L; ++i)
            x = chain_step(x, e[i + 1], wv[i], bv[i]);

        const float4 yl = e[L];
        float4 x2 = yl;
#pragma unroll
        for (int i = L - 1; i >= 0; --i)
            x2 = chain_step(x2, yl, wv[i], bv[i]);

        n1.x = fmaf(c, x.x, n1.x); n1.y = fmaf(c, x.y, n1.y);
        n1.z = fmaf(c, x.z, n1.z); n1.w = fmaf(c, x.w, n1.w);
        n2.x = fmaf(c, x2.x, n2.x); n2.y = fmaf(c, x2.y, n2.y);
        n2.z = fmaf(c, x2.z, n2.z); n2.w = fmaf(c, x2.w, n2.w);
    }

    s_red[(pq * 2 + 0) * 32 + dl] = n1;
    s_red[(pq * 2 + 1) * 32 + dl] = n2;
    __syncthreads();
    if (tid < 64) {
        const int half = tid >> 5, dq = tid & 31;
        float4 a = s_red[(0 * 2 + half) * 32 + dq];
#pragma unroll
        for (int q = 1; q < 8; ++q) {
            float4 t = s_red[(q * 2 + half) * 32 + dq];
            a.x += t.x; a.y += t.y; a.z += t.z; a.w += t.w;
        }
        float den = 0.f;
#pragma unroll
        for (int p = 0; p < NPATH; ++p) den += s_cnt[p];
        const float inv = 1.f / den;
        a.x *= inv; a.y *= inv; a.z *= inv; a.w *= inv;
        float4* hb = (float4*)(h + (size_t)b * DIN + gcol);
        hb[half * 32 + dq] = a;
    }
}

// Grid linearized 3*BATCH with g = bx % 3 so L=1/2/3 blocks interleave in
// dispatch order (even load through the tail).
__global__ __launch_bounds__(256) void groups_kernel(
    const int* __restrict__ e1, const int* __restrict__ m1, const float* __restrict__ c1,
    const int* __restrict__ e2, const int* __restrict__ m2, const float* __restrict__ c2,
    const int* __restrict__ e3, const int* __restrict__ m3, const float* __restrict__ c3,
    const float* __restrict__ E, const float* __restrict__ W, const float* __restrict__ Bm,
    float* __restrict__ h)
{
    __shared__ int s_idx[NPATH * 7 + NPATH];
    __shared__ float4 s_red[8 * 2 * 32];
    __shared__ float4 s_wb[192];            // W[3][32] + B[3][32] float4
    const float4* E4 = (const float4*)E;
    const float4* W4 = (const float4*)W;
    const float4* B4 = (const float4*)Bm;
    const int bx = blockIdx.x;
    const int g = bx % 3;
    const int b = bx / 3;
    if (g == 0)      group_body<1>(b, e1, m1, c1, E4, W4, B4, h, 0,   s_idx, s_red, s_wb);
    else if (g == 1) group_body<2>(b, e2, m2, c2, E4, W4, B4, h, 256, s_idx, s_red, s_wb);
    else             group_body<3>(b, e3, m3, c3, E4, W4, B4, h, 512, s_idx, s_red, s_wb);
}

// MLP head v7. L2 arithmetic that explains the stubborn ~45us: every thread
// streams its own 768 W1 dwords from L2 -> 786 MB L2->CU traffic (~23us floor
// at 34.5 TB/s) in ALL previous per-lane-global variants, independent of
// MROWS. Fix: serve the per-lane W1 stream from LDS (69 TB/s / 256B/cy/CU).
// Structure = round-0 compute (256 thr, MROWS=8, acc[4], identical k-ascending
// FMA order -> bitwise identical) + W1 in double-buffered KC=32 chunks with
// issue-early/write-late staging: next chunk's 4 float4 global loads issue
// BEFORE the current chunk's compute, drain into the other buffer after it.
// Hot loop: zero vmem — 4 conflict-free b32 w-reads (2-way = free) + 4
// wave-uniform b128 broadcasts + 16 FMA per 4k. LDS 61KB -> 2 blocks/CU.
// L2 staging traffic 512x393KB = 201MB (~6us, overlapped).
#define MROWS 8
#define KC 32
__global__ __launch_bounds__(256) void mlp_kernel(
    const float* __restrict__ h,
    const float* __restrict__ W1, const float* __restrict__ b1,
    const float* __restrict__ W2, const float* __restrict__ b2,
    const float* __restrict__ W3, const float* __restrict__ b3,
    float* __restrict__ out)
{
    __shared__ float hs[MROWS * DIN];       // 24 KB
    __shared__ float w1s[2][KC * C1];       // 2 x 16 KB
    __shared__ float h1[MROWS][C1];         // 4 KB
    __shared__ float h2[MROWS][C2];         // 1 KB

    const int tid = threadIdx.x;
    const int c = tid & 127;          // layer-1 column
    const int rh = tid >> 7;          // 0..1, owns rows rh*4 .. rh*4+3
    const int row0 = blockIdx.x * MROWS;

    {   // stage h tile (8x768 = 24KB), coalesced
        const float4* src = (const float4*)(h + (size_t)row0 * DIN);
        float4* dst = (float4*)hs;
#pragma unroll
        for (int i = 0; i < (MROWS * DIN / 4) / 256; ++i)      // 6
            dst[tid + i * 256] = src[tid + i * 256];
    }

    // prologue: stage W1 chunk 0 into buffer 0 (4 float4/thread, coalesced)
    {
        const float4* wsrc = (const float4*)W1;
        float4* wdst = (float4*)w1s[0];
#pragma unroll
        for (int i = 0; i < 4; ++i)
            wdst[tid + i * 256] = wsrc[tid + i * 256];
    }
    __syncthreads();   // hs + chunk 0 ready

    float acc[4];
    const float bias1 = b1[c];
#pragma unroll
    for (int r = 0; r < 4; ++r) acc[r] = bias1;

    const float* hrow = hs + rh * 4 * DIN;
    const int NCH = DIN / KC;                                  // 24 chunks
    for (int ch = 0; ch < NCH; ++ch) {
        // ---- issue next chunk's global loads EARLY (drain hides under compute)
        float4 wreg[4];
        if (ch + 1 < NCH) {
            const float4* wsrc = (const float4*)(W1 + (size_t)(ch + 1) * KC * C1);
#pragma unroll
            for (int i = 0; i < 4; ++i)
                wreg[i] = wsrc[tid + i * 256];
        }

        // ---- compute current chunk purely from LDS ----
        const float* wbuf = w1s[ch & 1];
        const int kb = ch * KC;
#pragma unroll 4
        for (int k0 = 0; k0 < KC; k0 += 4) {
            const float w0 = wbuf[(k0 + 0) * C1 + c];
            const float w1v = wbuf[(k0 + 1) * C1 + c];
            const float w2v = wbuf[(k0 + 2) * C1 + c];
            const float w3v = wbuf[(k0 + 3) * C1 + c];
#pragma unroll
            for (int r = 0; r < 4; ++r) {
                const float4 hq = *(const float4*)(hrow + r * DIN + kb + k0);
                acc[r] = fmaf(hq.x, w0, acc[r]);
                acc[r] = fmaf(hq.y, w1v, acc[r]);
                acc[r] = fmaf(hq.z, w2v, acc[r]);
                acc[r] = fmaf(hq.w, w3v, acc[r]);
            }
        }

        // ---- write next chunk into the other buffer, one barrier per chunk
        if (ch + 1 < NCH) {
            float4* wdst = (float4*)w1s[(ch + 1) & 1];
#pragma unroll
            for (int i = 0; i < 4; ++i)
                wdst[tid + i * 256] = wreg[i];
        }
        __syncthreads();
    }

#pragma unroll
    for (int r = 0; r < 4; ++r) h1[rh * 4 + r][c] = fmaxf(acc[r], 0.f);
    __syncthreads();

    // layer 2: 8 rows x 32 cols = 256 outputs, one per thread
    {
        const int r = tid >> 5;           // 0..7
        const int c2 = tid & 31;
        float a = b2[c2];
#pragma unroll
        for (int k = 0; k < C1; ++k)
            a = fmaf(h1[r][k], W2[k * C2 + c2], a);
        h2[r][c2] = fmaxf(a, 0.f);
    }
    __syncthreads();

    // layer 3
    if (tid < MROWS) {
        float a = b3[0];
#pragma unroll
        for (int k = 0; k < C2; ++k)
            a = fmaf(h2[tid][k], W3[k], a);
        out[row0 + tid] = a;
    }
}

extern "C" void kernel_launch(void* const* d_in, const int* in_sizes, int n_in,
                              void* d_out, int out_size, void* d_ws, size_t ws_size,
                              hipStream_t stream) {
    const int*   ent1 = (const int*)d_in[0];
    const int*   mid1 = (const int*)d_in[1];
    const float* cnt1 = (const float*)d_in[2];
    const int*   ent2 = (const int*)d_in[3];
    const int*   mid2 = (const int*)d_in[4];
    const float* cnt2 = (const float*)d_in[5];
    const int*   ent3 = (const int*)d_in[6];
    const int*   mid3 = (const int*)d_in[7];
    const float* cnt3 = (const float*)d_in[8];
    const float* E    = (const float*)d_in[9];
    const float* W    = (const float*)d_in[10];
    const float* Bm   = (const float*)d_in[11];
    const float* W1   = (const float*)d_in[12];
    const float* b1   = (const float*)d_in[13];
    const float* W2   = (const float*)d_in[14];
    const float* b2   = (const float*)d_in[15];
    const float* W3   = (const float*)d_in[16];
    const float* b3   = (const float*)d_in[17];

    float* h = (float*)d_ws;   // [BATCH, 768]
    float* out = (float*)d_out;

    groups_kernel<<<3 * BATCH, 256, 0, stream>>>(ent1, mid1, cnt1, ent2, mid2, cnt2,
                                                 ent3, mid3, cnt3, E, W, Bm, h);
    mlp_kernel<<<BATCH / MROWS, 256, 0, stream>>>(h, W1, b1, W2, b2, W3, b3, out);
}

// Round 9
// 213.569 us; speedup vs baseline: 1.2201x; 1.2201x over previous
//
#include <hip/hip_runtime.h>

#define EMBED 128
#define NPATH 32
#define BATCH 4096
#define DIN 768
#define C1 128
#define C2 32

__device__ __forceinline__ float4 chain_step(float4 x, float4 y, float4 wm, float4 bm) {
    float4 r;
    r.x = fmaxf(fmaf(x.x * wm.x, y.x, bm.x), 0.f);
    r.y = fmaxf(fmaf(x.y * wm.y, y.y, bm.y), 0.f);
    r.z = fmaxf(fmaf(x.z * wm.z, y.z, bm.z), 0.f);
    r.w = fmaxf(fmaf(x.w * wm.w, y.w, bm.w), 0.f);
    return r;
}

// One group-unit for batch row b. 256 threads: dl = tid&31 owns dims 4*dl..4*dl+3
// (float4), pq = tid>>5 (0..7) owns paths p = pq, pq+8, pq+16, pq+24.
// FINAL (rounds 0-7): memory-pattern-bound at ~3.55 TB/s / ~83us — five
// structural variants plateau here; random 512B gathers over the 51MB
// E-table are the floor. W/B selection via LDS gather (VALU-lean, Occ 62%).
template<int L>
__device__ __forceinline__ void group_body(
    int b, const int* __restrict__ ent, const int* __restrict__ mid,
    const float* __restrict__ counts, const float4* __restrict__ E4,
    const float4* __restrict__ W4, const float4* __restrict__ B4,
    float* __restrict__ h, int gcol, int* s_idx, float4* s_red, float4* s_wb)
{
    const int tid = threadIdx.x;
    const int dl = tid & 31;
    const int pq = tid >> 5;

    int* s_ent = s_idx;
    int* s_mid = s_idx + NPATH * (L + 1);
    float* s_cnt = (float*)(s_idx + NPATH * (2 * L + 1));
    float4* s_w4 = s_wb;          // [3][32] float4
    float4* s_b4 = s_wb + 96;     // [3][32] float4

    const int* entb = ent + (size_t)b * (NPATH * (L + 1));
    const int* midb = mid + (size_t)b * (NPATH * L);
    for (int i = tid; i < NPATH * (L + 1); i += 256) s_ent[i] = entb[i];
    for (int i = tid; i < NPATH * L; i += 256) s_mid[i] = midb[i];
    if (tid < NPATH) s_cnt[tid] = counts[(size_t)b * NPATH + tid];
    if (tid < 96) { s_w4[tid] = W4[tid]; s_b4[tid] = B4[tid]; }
    __syncthreads();

    float4 n1 = make_float4(0.f, 0.f, 0.f, 0.f);
    float4 n2 = make_float4(0.f, 0.f, 0.f, 0.f);

#pragma unroll 2
    for (int j = 0; j < NPATH / 8; ++j) {
        const int p = pq + 8 * j;
        int ei[L + 1], mi[L];
#pragma unroll
        for (int i = 0; i <= L; ++i) ei[i] = s_ent[p * (L + 1) + i];
#pragma unroll
        for (int i = 0; i < L; ++i) mi[i] = s_mid[p * L + i];

        float4 e[L + 1];
#pragma unroll
        for (int i = 0; i <= L; ++i) e[i] = E4[(size_t)ei[i] * 32 + dl];

        float4 wv[L], bv[L];
#pragma unroll
        for (int i = 0; i < L; ++i) {
            wv[i] = s_w4[mi[i] * 32 + dl];
            bv[i] = s_b4[mi[i] * 32 + dl];
        }
        const float c = s_cnt[p];

        float4 x = e[0];
#pragma unroll
        for (int i = 0; i < L; ++i)
            x = chain_step(x, e[i + 1], wv[i], bv[i]);

        const float4 yl = e[L];
        float4 x2 = yl;
#pragma unroll
        for (int i = L - 1; i >= 0; --i)
            x2 = chain_step(x2, yl, wv[i], bv[i]);

        n1.x = fmaf(c, x.x, n1.x); n1.y = fmaf(c, x.y, n1.y);
        n1.z = fmaf(c, x.z, n1.z); n1.w = fmaf(c, x.w, n1.w);
        n2.x = fmaf(c, x2.x, n2.x); n2.y = fmaf(c, x2.y, n2.y);
        n2.z = fmaf(c, x2.z, n2.z); n2.w = fmaf(c, x2.w, n2.w);
    }

    s_red[(pq * 2 + 0) * 32 + dl] = n1;
    s_red[(pq * 2 + 1) * 32 + dl] = n2;
    __syncthreads();
    if (tid < 64) {
        const int half = tid >> 5, dq = tid & 31;
        float4 a = s_red[(0 * 2 + half) * 32 + dq];
#pragma unroll
        for (int q = 1; q < 8; ++q) {
            float4 t = s_red[(q * 2 + half) * 32 + dq];
            a.x += t.x; a.y += t.y; a.z += t.z; a.w += t.w;
        }
        float den = 0.f;
#pragma unroll
        for (int p = 0; p < NPATH; ++p) den += s_cnt[p];
        const float inv = 1.f / den;
        a.x *= inv; a.y *= inv; a.z *= inv; a.w *= inv;
        float4* hb = (float4*)(h + (size_t)b * DIN + gcol);
        hb[half * 32 + dq] = a;
    }
}

// Grid linearized 3*BATCH with g = bx % 3 so L=1/2/3 blocks interleave in
// dispatch order (even load through the tail).
__global__ __launch_bounds__(256) void groups_kernel(
    const int* __restrict__ e1, const int* __restrict__ m1, const float* __restrict__ c1,
    const int* __restrict__ e2, const int* __restrict__ m2, const float* __restrict__ c2,
    const int* __restrict__ e3, const int* __restrict__ m3, const float* __restrict__ c3,
    const float* __restrict__ E, const float* __restrict__ W, const float* __restrict__ Bm,
    float* __restrict__ h)
{
    __shared__ int s_idx[NPATH * 7 + NPATH];
    __shared__ float4 s_red[8 * 2 * 32];
    __shared__ float4 s_wb[192];            // W[3][32] + B[3][32] float4
    const float4* E4 = (const float4*)E;
    const float4* W4 = (const float4*)W;
    const float4* B4 = (const float4*)Bm;
    const int bx = blockIdx.x;
    const int g = bx % 3;
    const int b = bx / 3;
    if (g == 0)      group_body<1>(b, e1, m1, c1, E4, W4, B4, h, 0,   s_idx, s_red, s_wb);
    else if (g == 1) group_body<2>(b, e2, m2, c2, E4, W4, B4, h, 256, s_idx, s_red, s_wb);
    else             group_body<3>(b, e3, m3, c3, E4, W4, B4, h, 512, s_idx, s_red, s_wb);
}

// MLP head — EXACT round-0 structure, the fastest measured variant (~40us).
// Session ledger for this kernel: per-lane-global variants (r0/r3/r5/r6) all
// 40-51us; LDS-staged W1 variants (r4 KC=96, r7 dbuf KC=32, r4-scalar) all
// 85-95us (barrier serialization at 8 waves/CU costs more than the L2 stream
// it saves). ILP (r2 unroll-8) and TLP (r3/r6, 16 waves/CU) both neutral-to-
// negative. Keeping the empirical optimum.
#define MROWS 8
__global__ __launch_bounds__(256) void mlp_kernel(
    const float* __restrict__ h,
    const float* __restrict__ W1, const float* __restrict__ b1,
    const float* __restrict__ W2, const float* __restrict__ b2,
    const float* __restrict__ W3, const float* __restrict__ b3,
    float* __restrict__ out)
{
    const int tid = threadIdx.x;
    const int c = tid & 127;          // layer-1 column
    const int rh = tid >> 7;          // 0..1, owns rows rh*4 .. rh*4+3
    const int row0 = blockIdx.x * MROWS;

    __shared__ float hs[MROWS * DIN];     // 24 KB, rows contiguous
    {
        const float4* src = (const float4*)(h + (size_t)row0 * DIN);
        float4* dst = (float4*)hs;
#pragma unroll
        for (int i = 0; i < (MROWS * DIN / 4) / 256; ++i)
            dst[tid + i * 256] = src[tid + i * 256];   // 6 coalesced float4 / thread
    }
    __syncthreads();

    float acc[4];
    const float bias1 = b1[c];
#pragma unroll
    for (int r = 0; r < 4; ++r) acc[r] = bias1;

    const float* hrow = hs + rh * 4 * DIN;
    for (int k0 = 0; k0 < DIN; k0 += 4) {
        // 4 coalesced W1 dwords + 4 LDS b128 broadcasts + 16 FMA
        float w0 = W1[(k0 + 0) * C1 + c];
        float w1 = W1[(k0 + 1) * C1 + c];
        float w2 = W1[(k0 + 2) * C1 + c];
        float w3 = W1[(k0 + 3) * C1 + c];
#pragma unroll
        for (int r = 0; r < 4; ++r) {
            const float4 hq = *(const float4*)(hrow + r * DIN + k0);
            acc[r] = fmaf(hq.x, w0, acc[r]);
            acc[r] = fmaf(hq.y, w1, acc[r]);
            acc[r] = fmaf(hq.z, w2, acc[r]);
            acc[r] = fmaf(hq.w, w3, acc[r]);
        }
    }

    __shared__ float h1[MROWS][C1];
#pragma unroll
    for (int r = 0; r < 4; ++r) h1[rh * 4 + r][c] = fmaxf(acc[r], 0.f);
    __syncthreads();

    // layer 2: 8 rows x 32 cols = 256 outputs, one per thread
    __shared__ float h2[MROWS][C2];
    {
        const int r = tid >> 5;           // 0..7
        const int c2 = tid & 31;
        float a = b2[c2];
#pragma unroll
        for (int k = 0; k < C1; ++k)
            a = fmaf(h1[r][k], W2[k * C2 + c2], a);
        h2[r][c2] = fmaxf(a, 0.f);
    }
    __syncthreads();

    // layer 3
    if (tid < MROWS) {
        float a = b3[0];
#pragma unroll
        for (int k = 0; k < C2; ++k)
            a = fmaf(h2[tid][k], W3[k], a);
        out[row0 + tid] = a;
    }
}

extern "C" void kernel_launch(void* const* d_in, const int* in_sizes, int n_in,
                              void* d_out, int out_size, void* d_ws, size_t ws_size,
                              hipStream_t stream) {
    const int*   ent1 = (const int*)d_in[0];
    const int*   mid1 = (const int*)d_in[1];
    const float* cnt1 = (const float*)d_in[2];
    const int*   ent2 = (const int*)d_in[3];
    const int*   mid2 = (const int*)d_in[4];
    const float* cnt2 = (const float*)d_in[5];
    const int*   ent3 = (const int*)d_in[6];
    const int*   mid3 = (const int*)d_in[7];
    const float* cnt3 = (const float*)d_in[8];
    const float* E    = (const float*)d_in[9];
    const float* W    = (const float*)d_in[10];
    const float* Bm   = (const float*)d_in[11];
    const float* W1   = (const float*)d_in[12];
    const float* b1   = (const float*)d_in[13];
    const float* W2   = (const float*)d_in[14];
    const float* b2   = (const float*)d_in[15];
    const float* W3   = (const float*)d_in[16];
    const float* b3   = (const float*)d_in[17];

    float* h = (float*)d_ws;   // [BATCH, 768]
    float* out = (float*)d_out;

    dim3 unused(0);
    groups_kernel<<<3 * BATCH, 256, 0, stream>>>(ent1, mid1, cnt1, ent2, mid2, cnt2,
                                                 ent3, mid3, cnt3, E, W, Bm, h);
    mlp_kernel<<<BATCH / MROWS, 256, 0, stream>>>(h, W1, b1, W2, b2, W3, b3, out);
}